// Round 1
// baseline (419.245 us; speedup 1.0000x reference)
//
#include <hip/hip_runtime.h>
#include <hip/hip_bf16.h>
#include <stdint.h>

typedef unsigned short u16;
typedef unsigned int u32;
typedef __attribute__((ext_vector_type(8))) short short8;   // 8 bf16 (4 VGPRs) MFMA operand
typedef __attribute__((ext_vector_type(4))) float f32x4;    // MFMA accumulator
typedef __attribute__((ext_vector_type(4))) unsigned short u16x4;

#define DEVFN static __device__ __forceinline__

// ---------- helpers ----------

DEVFN u16 f2bf(float f) {  // RNE float->bf16 (finite inputs)
  u32 u = __float_as_uint(f);
  u = (u + 0x7FFFu + ((u >> 16) & 1u)) >> 16;
  return (u16)u;
}

DEVFN void gll16(const void* g, void* l) {  // async global->LDS, 16B/lane
  __builtin_amdgcn_global_load_lds((const __attribute__((address_space(1))) u32*)g,
                                   (__attribute__((address_space(3))) u32*)l, 16, 0, 0);
}

// ---------- small kernels: adaptive scale path ----------

// grid 256 = B * 128 chunks of 16 rows; 256 threads. Partial column sums -> atomicAdd.
__global__ void ctx_partial_kernel(const float* __restrict__ x, float* __restrict__ ctx) {
  int blk = blockIdx.x;
  int b = blk >> 7;
  int s0 = (blk & 127) * 16;
  int t = threadIdx.x;
  const float* xb = x + (size_t)b * 2048 * 1024 + (size_t)s0 * 1024;
#pragma unroll
  for (int c = 0; c < 4; ++c) {
    int d = c * 256 + t;
    float sum = 0.f;
#pragma unroll
    for (int s = 0; s < 16; ++s) sum += xb[(size_t)s * 1024 + d];
    atomicAdd(&ctx[b * 1024 + d], sum);
  }
}

// grid B, 256 threads: h = gelu(ctx/2048 @ W1 + b1); af = sigmoid(h @ W2 + b2); scale[b]
__global__ void adaptive_kernel(const float* __restrict__ ctx, const float* __restrict__ W1,
                                const float* __restrict__ b1, const float* __restrict__ W2,
                                const float* __restrict__ b2, const float* __restrict__ aw,
                                float* __restrict__ scale) {
  int b = blockIdx.x;
  int t = threadIdx.x;
  __shared__ float ctxs[1024];
  __shared__ float hs[512];
  __shared__ float afs[16];
  for (int i = t; i < 1024; i += 256) ctxs[i] = ctx[b * 1024 + i] * (1.0f / 2048.0f);
  __syncthreads();
  for (int j = t; j < 512; j += 256) {
    float acc = b1[j];
    for (int d = 0; d < 1024; ++d) acc += ctxs[d] * W1[(size_t)d * 512 + j];
    hs[j] = 0.5f * acc * (1.0f + erff(acc * 0.70710678118654752f));  // exact gelu
  }
  __syncthreads();
  if (t < 16) {
    float acc = b2[t];
    for (int j = 0; j < 512; ++j) acc += hs[j] * W2[(size_t)j * 16 + t];
    afs[t] = 1.0f / (1.0f + __expf(-acc));
  }
  __syncthreads();
  if (t == 0) {
    float s = 0.f;
    for (int i = 0; i < 16; ++i) s += afs[i];
    scale[b] = 1.0f + aw[0] * (s * (1.0f / 16.0f));
  }
}

// ---------- conversion / transpose ----------

__global__ void cvt_bf16_kernel(const float* __restrict__ in, u16* __restrict__ out, int n4) {
  int i = blockIdx.x * blockDim.x + threadIdx.x;
  if (i < n4) {
    float4 v = ((const float4*)in)[i];
    u16x4 o = {f2bf(v.x), f2bf(v.y), f2bf(v.z), f2bf(v.w)};
    ((u16x4*)out)[i] = o;
  }
}

// in: fp32 [K][N] row-major -> out: bf16 [N][K] row-major. grid (N/32, K/32), 256 thr.
__global__ void transpose_bf16_kernel(const float* __restrict__ in, u16* __restrict__ out,
                                      int K, int N) {
  __shared__ u16 tile[32][33];
  int n0 = blockIdx.x * 32, k0 = blockIdx.y * 32;
  int tc = threadIdx.x & 31, tr = threadIdx.x >> 5;  // tr in 0..7
  for (int i = tr; i < 32; i += 8)
    tile[i][tc] = f2bf(in[(size_t)(k0 + i) * N + n0 + tc]);
  __syncthreads();
  for (int i = tr; i < 32; i += 8)
    out[(size_t)(n0 + i) * K + k0 + tc] = tile[tc][i];
}

// ---------- GEMM mainloop (m97 structure: 128x128 tile, BK=32, 4 waves) ----------
// C = A(MxK bf16 rowmajor) @ Bt(NxK bf16 rowmajor)^T, fp32 acc. K multiple of 32.

DEVFN void gemm_tile_mainloop(const u16* __restrict__ A, const u16* __restrict__ Bt,
                              int m0, int n0, int K, u16* As, u16* Bs, f32x4 acc[4][4]) {
  const int tid = threadIdx.x;
  const int lane = tid & 63, wid = tid >> 6;
  const int wr = wid >> 1, wc = wid & 1;
  const int lr = lane & 15, lg = lane >> 4;

  const u16* ag0 = A + (size_t)(m0 + (tid >> 2)) * K + (tid & 3) * 8;
  const u16* ag1 = ag0 + (size_t)64 * K;
  const u16* bg0 = Bt + (size_t)(n0 + (tid >> 2)) * K + (tid & 3) * 8;
  const u16* bg1 = bg0 + (size_t)64 * K;
  u16* as0 = As + tid * 8;
  u16* as1 = As + (tid + 256) * 8;
  u16* bs0 = Bs + tid * 8;
  u16* bs1 = Bs + (tid + 256) * 8;

  for (int k0 = 0; k0 < K; k0 += 32) {
    gll16(ag0 + k0, as0);
    gll16(ag1 + k0, as1);
    gll16(bg0 + k0, bs0);
    gll16(bg1 + k0, bs1);
    __syncthreads();  // staged data visible (compiler drains vmcnt before barrier)
    short8 af[4], bf[4];
#pragma unroll
    for (int i = 0; i < 4; ++i)
      af[i] = *(const short8*)&As[(wr * 64 + i * 16 + lr) * 32 + lg * 8];
#pragma unroll
    for (int j = 0; j < 4; ++j)
      bf[j] = *(const short8*)&Bs[(wc * 64 + j * 16 + lr) * 32 + lg * 8];
#pragma unroll
    for (int i = 0; i < 4; ++i)
#pragma unroll
      for (int j = 0; j < 4; ++j)
        acc[i][j] = __builtin_amdgcn_mfma_f32_16x16x32_bf16(af[i], bf[j], acc[i][j], 0, 0, 0);
    __syncthreads();  // all waves done reading before next stage
  }
}

// GEMM1: qkv = x_bf16 @ WqkvT^T + bqkv, split-written as Q[b,s,h,d], K[b,s,h,d] (bf16)
// and V^T[b,h,d,s] (bf16) for the attention PV step.
__global__ __launch_bounds__(256) void gemm_qkv_kernel(
    const u16* __restrict__ A, const u16* __restrict__ Bt, const float* __restrict__ bias,
    u16* __restrict__ Qb, u16* __restrict__ Kb, u16* __restrict__ Vt) {
  __shared__ __align__(16) u16 As[128 * 32];
  __shared__ __align__(16) u16 Bs[128 * 32];
  f32x4 acc[4][4];
  const f32x4 z = {0.f, 0.f, 0.f, 0.f};
#pragma unroll
  for (int i = 0; i < 4; ++i)
#pragma unroll
    for (int j = 0; j < 4; ++j) acc[i][j] = z;
  int m0 = blockIdx.y * 128, n0 = blockIdx.x * 128;
  gemm_tile_mainloop(A, Bt, m0, n0, 1024, As, Bs, acc);

  const int lane = threadIdx.x & 63, wid = threadIdx.x >> 6;
  const int wr = wid >> 1, wc = wid & 1, lr = lane & 15, lg = lane >> 4;
#pragma unroll
  for (int j = 0; j < 4; ++j) {
    int col = n0 + wc * 64 + j * 16 + lr;
    float bv = bias[col];
    int c3 = col >> 10;          // uniform per block (128 | 1024)
    int hh = (col >> 6) & 15, dd = col & 63;
#pragma unroll
    for (int i = 0; i < 4; ++i) {
#pragma unroll
      for (int r = 0; r < 4; ++r) {
        int row = m0 + wr * 64 + i * 16 + lg * 4 + r;  // C: col=lane&15, row=(lane>>4)*4+r
        u16 v = f2bf(acc[i][j][r] + bv);
        if (c3 == 0)
          Qb[(size_t)row * 1024 + (col & 1023)] = v;
        else if (c3 == 1)
          Kb[(size_t)row * 1024 + (col & 1023)] = v;
        else {
          int b = row >> 11, s = row & 2047;
          Vt[(((size_t)b * 16 + hh) * 64 + dd) * 2048 + s] = v;
        }
      }
    }
  }
}

// GEMM2: out = (attn_bf16 @ WoT^T + bo) * scale[b], fp32 out.
__global__ __launch_bounds__(256) void gemm_out_kernel(
    const u16* __restrict__ A, const u16* __restrict__ Bt, const float* __restrict__ bo,
    const float* __restrict__ scale, float* __restrict__ out) {
  __shared__ __align__(16) u16 As[128 * 32];
  __shared__ __align__(16) u16 Bs[128 * 32];
  f32x4 acc[4][4];
  const f32x4 z = {0.f, 0.f, 0.f, 0.f};
#pragma unroll
  for (int i = 0; i < 4; ++i)
#pragma unroll
    for (int j = 0; j < 4; ++j) acc[i][j] = z;
  int m0 = blockIdx.y * 128, n0 = blockIdx.x * 128;
  gemm_tile_mainloop(A, Bt, m0, n0, 1024, As, Bs, acc);

  const int lane = threadIdx.x & 63, wid = threadIdx.x >> 6;
  const int wr = wid >> 1, wc = wid & 1, lr = lane & 15, lg = lane >> 4;
#pragma unroll
  for (int j = 0; j < 4; ++j) {
    int col = n0 + wc * 64 + j * 16 + lr;
    float bv = bo[col];
#pragma unroll
    for (int i = 0; i < 4; ++i) {
#pragma unroll
      for (int r = 0; r < 4; ++r) {
        int row = m0 + wr * 64 + i * 16 + lg * 4 + r;
        out[(size_t)row * 1024 + col] = (acc[i][j][r] + bv) * scale[row >> 11];
      }
    }
  }
}

// ---------- flash attention with mobius score transform ----------
// grid = B*H*32 blocks (64-query tile each), 256 threads = 4 waves, wave w owns 16 queries.
// Swapped QK^T: St = mfma(K_frag, Q_frag) -> lane holds 16 keys of ONE query (q = lane&15).
__global__ __launch_bounds__(256) void attn_kernel(
    const u16* __restrict__ Qb, const u16* __restrict__ Kb, const u16* __restrict__ Vt,
    const float* __restrict__ mobius, u16* __restrict__ O) {
  __shared__ __align__(16) u16 Qs[64 * 64];
  __shared__ __align__(16) u16 Ks[64 * 64];
  __shared__ __align__(16) u16 Vs[64 * 64];  // V^T tile: [d][key]
  __shared__ __align__(16) u16 Ps[64 * 64];  // P tile: [query][key], per-wave 16-row region
  const int tid = threadIdx.x;
  const int lane = tid & 63, w = tid >> 6;
  const int lr = lane & 15, lg = lane >> 4;
  const int bidx = blockIdx.x;
  const int qb = bidx & 31, h = (bidx >> 5) & 15, b = bidx >> 9;
  const float msc = mobius[h];

  {  // stage Q tile once: rows = 64 queries, 64 dh bf16 each (128B)
    const u16* qg = Qb + (size_t)(b * 2048 + qb * 64 + (tid >> 3)) * 1024 + h * 64 + (tid & 7) * 8;
    gll16(qg, Qs + tid * 8);
    gll16(qg + (size_t)32 * 1024, Qs + (tid + 256) * 8);
  }
  const u16* kg = Kb + (size_t)(b * 2048 + (tid >> 3)) * 1024 + h * 64 + (tid & 7) * 8;
  const u16* vg = Vt + ((size_t)(b * 16 + h) * 64 + (tid >> 3)) * 2048 + (tid & 7) * 8;

  float m_run = -3.0e38f, l_run = 0.0f;
  f32x4 acc_o[4];
  const f32x4 z = {0.f, 0.f, 0.f, 0.f};
#pragma unroll
  for (int i = 0; i < 4; ++i) acc_o[i] = z;

  for (int kt = 0; kt < 32; ++kt) {
    __syncthreads();  // all waves done with prev K/V tile (and Q staged on iter 0)
    gll16(kg + (size_t)kt * 64 * 1024, Ks + tid * 8);
    gll16(kg + (size_t)kt * 64 * 1024 + (size_t)32 * 1024, Ks + (tid + 256) * 8);
    gll16(vg + kt * 64, Vs + tid * 8);
    gll16(vg + kt * 64 + 32 * 2048, Vs + (tid + 256) * 8);
    __syncthreads();

    // St = K_tile @ Q_wave^T : fragments (key-tile ki) x (wave's 16 queries)
    f32x4 sacc[4];
#pragma unroll
    for (int i = 0; i < 4; ++i) sacc[i] = z;
#pragma unroll
    for (int ks = 0; ks < 2; ++ks) {
      short8 qf = *(const short8*)&Qs[(w * 16 + lr) * 64 + ks * 32 + lg * 8];
#pragma unroll
      for (int ki = 0; ki < 4; ++ki) {
        short8 kf = *(const short8*)&Ks[(ki * 16 + lr) * 64 + ks * 32 + lg * 8];
        sacc[ki] = __builtin_amdgcn_mfma_f32_16x16x32_bf16(kf, qf, sacc[ki], 0, 0, 0);
      }
    }

    // scale + mobius + online softmax. lane's query = lane&15; keys ki*16+lg*4+r.
    float p[16];
    float tmax = -3.0e38f;
#pragma unroll
    for (int ki = 0; ki < 4; ++ki)
#pragma unroll
      for (int r = 0; r < 4; ++r) {
        float s = sacc[ki][r] * 0.125f;
        s += msc * s / (1.0f + s * s);
        p[ki * 4 + r] = s;
        tmax = fmaxf(tmax, s);
      }
    tmax = fmaxf(tmax, __shfl_xor(tmax, 16));
    tmax = fmaxf(tmax, __shfl_xor(tmax, 32));
    float m_new = fmaxf(m_run, tmax);
    float corr = __expf(m_run - m_new);
    float tsum = 0.f;
#pragma unroll
    for (int i = 0; i < 16; ++i) {
      p[i] = __expf(p[i] - m_new);
      tsum += p[i];
    }
    tsum += __shfl_xor(tsum, 16);
    tsum += __shfl_xor(tsum, 32);
    l_run = l_run * corr + tsum;
    m_run = m_new;

    // write P (bf16) into this wave's private region: P[query][key]
#pragma unroll
    for (int ki = 0; ki < 4; ++ki) {
      u16x4 pk = {f2bf(p[ki * 4 + 0]), f2bf(p[ki * 4 + 1]), f2bf(p[ki * 4 + 2]),
                  f2bf(p[ki * 4 + 3])};
      *(u16x4*)&Ps[(w * 16 + lr) * 64 + ki * 16 + lg * 4] = pk;
    }

    // rescale O: O-fragment row(query) = lg*4+r, corr lives at lane (query)
    float c4[4];
#pragma unroll
    for (int r = 0; r < 4; ++r) c4[r] = __shfl(corr, lg * 4 + r);
#pragma unroll
    for (int di = 0; di < 4; ++di)
#pragma unroll
      for (int r = 0; r < 4; ++r) acc_o[di][r] *= c4[r];

    // O += P @ V  (A = P[q][key] rows, B^T = Vs[d][key] rows)
#pragma unroll
    for (int ks = 0; ks < 2; ++ks) {
      short8 pf = *(const short8*)&Ps[(w * 16 + lr) * 64 + ks * 32 + lg * 8];
#pragma unroll
      for (int di = 0; di < 4; ++di) {
        short8 vf = *(const short8*)&Vs[(di * 16 + lr) * 64 + ks * 32 + lg * 8];
        acc_o[di] = __builtin_amdgcn_mfma_f32_16x16x32_bf16(pf, vf, acc_o[di], 0, 0, 0);
      }
    }
  }

  float linv = 1.0f / l_run;
  float li[4];
#pragma unroll
  for (int r = 0; r < 4; ++r) li[r] = __shfl(linv, lg * 4 + r);
  size_t obase = (size_t)(b * 2048 + qb * 64 + w * 16) * 1024 + h * 64;
#pragma unroll
  for (int di = 0; di < 4; ++di)
#pragma unroll
    for (int r = 0; r < 4; ++r)
      O[obase + (size_t)(lg * 4 + r) * 1024 + di * 16 + lr] = f2bf(acc_o[di][r] * li[r]);
}

// ---------- launch ----------

extern "C" void kernel_launch(void* const* d_in, const int* in_sizes, int n_in,
                              void* d_out, int out_size, void* d_ws, size_t ws_size,
                              hipStream_t stream) {
  const float* x = (const float*)d_in[0];
  const float* Wqkv = (const float*)d_in[1];
  const float* bqkv = (const float*)d_in[2];
  const float* Wo = (const float*)d_in[3];
  const float* bo = (const float*)d_in[4];
  const float* mob = (const float*)d_in[5];
  const float* W1 = (const float*)d_in[6];
  const float* b1 = (const float*)d_in[7];
  const float* W2 = (const float*)d_in[8];
  const float* b2 = (const float*)d_in[9];
  const float* aw = (const float*)d_in[10];
  float* out = (float*)d_out;

  char* ws = (char*)d_ws;
  float* scale = (float*)ws;               // 2 floats
  float* ctx = (float*)(ws + 256);         // 2048 floats
  u16* xbf = (u16*)(ws + 16384);           // 4096x1024
  u16* wqkvT = xbf + (size_t)4096 * 1024;  // 3072x1024
  u16* woT = wqkvT + (size_t)3072 * 1024;  // 1024x1024
  u16* Qb = woT + (size_t)1024 * 1024;     // [B,S,H,64]
  u16* Kb = Qb + (size_t)4096 * 1024;      // [B,S,H,64]
  u16* Vt = Kb + (size_t)4096 * 1024;      // [B,H,64,S]
  u16* attn = Vt + (size_t)4096 * 1024;    // [B,S,D]
  // total: 16KB + 48MB

  hipMemsetAsync(ctx, 0, 2048 * sizeof(float), stream);
  ctx_partial_kernel<<<256, 256, 0, stream>>>(x, ctx);
  adaptive_kernel<<<2, 256, 0, stream>>>(ctx, W1, b1, W2, b2, aw, scale);
  cvt_bf16_kernel<<<4096, 256, 0, stream>>>(x, xbf, 1048576);
  transpose_bf16_kernel<<<dim3(96, 32), 256, 0, stream>>>(Wqkv, wqkvT, 1024, 3072);
  transpose_bf16_kernel<<<dim3(32, 32), 256, 0, stream>>>(Wo, woT, 1024, 1024);
  gemm_qkv_kernel<<<dim3(24, 32), 256, 0, stream>>>(xbf, wqkvT, bqkv, Qb, Kb, Vt);
  attn_kernel<<<1024, 256, 0, stream>>>(Qb, Kb, Vt, mob, attn);
  gemm_out_kernel<<<dim3(8, 32), 256, 0, stream>>>(attn, woT, bo, scale, out);
}

// Round 2
// 368.986 us; speedup vs baseline: 1.1362x; 1.1362x over previous
//
#include <hip/hip_runtime.h>
#include <hip/hip_bf16.h>
#include <stdint.h>

typedef unsigned short u16;
typedef unsigned int u32;
typedef __attribute__((ext_vector_type(8))) short short8;   // 8 bf16 (4 VGPRs) MFMA operand
typedef __attribute__((ext_vector_type(4))) float f32x4;    // MFMA accumulator
typedef __attribute__((ext_vector_type(4))) unsigned short u16x4;

#define DEVFN static __device__ __forceinline__

// ---------- helpers ----------

DEVFN u16 f2bf(float f) {  // RNE float->bf16 (finite inputs)
  u32 u = __float_as_uint(f);
  u = (u + 0x7FFFu + ((u >> 16) & 1u)) >> 16;
  return (u16)u;
}

DEVFN void gll16(const void* g, void* l) {  // async global->LDS, 16B/lane
  __builtin_amdgcn_global_load_lds((const __attribute__((address_space(1))) u32*)g,
                                   (__attribute__((address_space(3))) u32*)l, 16, 0, 0);
}

// ---------- small kernels: adaptive scale path ----------

__global__ void ctx_partial_kernel(const float* __restrict__ x, float* __restrict__ ctx) {
  int blk = blockIdx.x;
  int b = blk >> 7;
  int s0 = (blk & 127) * 16;
  int t = threadIdx.x;
  const float* xb = x + (size_t)b * 2048 * 1024 + (size_t)s0 * 1024;
#pragma unroll
  for (int c = 0; c < 4; ++c) {
    int d = c * 256 + t;
    float sum = 0.f;
#pragma unroll
    for (int s = 0; s < 16; ++s) sum += xb[(size_t)s * 1024 + d];
    atomicAdd(&ctx[b * 1024 + d], sum);
  }
}

__global__ void adaptive_kernel(const float* __restrict__ ctx, const float* __restrict__ W1,
                                const float* __restrict__ b1, const float* __restrict__ W2,
                                const float* __restrict__ b2, const float* __restrict__ aw,
                                float* __restrict__ scale) {
  int b = blockIdx.x;
  int t = threadIdx.x;
  __shared__ float ctxs[1024];
  __shared__ float hs[512];
  __shared__ float afs[16];
  for (int i = t; i < 1024; i += 256) ctxs[i] = ctx[b * 1024 + i] * (1.0f / 2048.0f);
  __syncthreads();
  for (int j = t; j < 512; j += 256) {
    float a0 = 0.f, a1 = 0.f, a2 = 0.f, a3 = 0.f;  // 4-way chain split
    for (int d = 0; d < 1024; d += 4) {
      a0 += ctxs[d + 0] * W1[(size_t)(d + 0) * 512 + j];
      a1 += ctxs[d + 1] * W1[(size_t)(d + 1) * 512 + j];
      a2 += ctxs[d + 2] * W1[(size_t)(d + 2) * 512 + j];
      a3 += ctxs[d + 3] * W1[(size_t)(d + 3) * 512 + j];
    }
    float acc = b1[j] + ((a0 + a1) + (a2 + a3));
    hs[j] = 0.5f * acc * (1.0f + erff(acc * 0.70710678118654752f));  // exact gelu
  }
  __syncthreads();
  if (t < 16) {
    float a0 = 0.f, a1 = 0.f;
    for (int j = 0; j < 512; j += 2) {
      a0 += hs[j] * W2[(size_t)j * 16 + t];
      a1 += hs[j + 1] * W2[(size_t)(j + 1) * 16 + t];
    }
    float acc = b2[t] + a0 + a1;
    afs[t] = 1.0f / (1.0f + __expf(-acc));
  }
  __syncthreads();
  if (t == 0) {
    float s = 0.f;
    for (int i = 0; i < 16; ++i) s += afs[i];
    scale[b] = 1.0f + aw[0] * (s * (1.0f / 16.0f));
  }
}

// ---------- conversion / transpose ----------

__global__ void cvt_bf16_kernel(const float* __restrict__ in, u16* __restrict__ out, int n4) {
  int i = blockIdx.x * blockDim.x + threadIdx.x;
  if (i < n4) {
    float4 v = ((const float4*)in)[i];
    u16x4 o = {f2bf(v.x), f2bf(v.y), f2bf(v.z), f2bf(v.w)};
    ((u16x4*)out)[i] = o;
  }
}

// in: fp32 [K][N] row-major -> out: bf16 [N][K] row-major. grid (N/32, K/32), 256 thr.
__global__ void transpose_bf16_kernel(const float* __restrict__ in, u16* __restrict__ out,
                                      int K, int N) {
  __shared__ u16 tile[32][33];
  int n0 = blockIdx.x * 32, k0 = blockIdx.y * 32;
  int tc = threadIdx.x & 31, tr = threadIdx.x >> 5;  // tr in 0..7
  for (int i = tr; i < 32; i += 8)
    tile[i][tc] = f2bf(in[(size_t)(k0 + i) * N + n0 + tc]);
  __syncthreads();
  for (int i = tr; i < 32; i += 8)
    out[(size_t)(n0 + i) * K + k0 + tc] = tile[tc][i];
}

// ---------- GEMM mainloops: swizzled LDS + 2-phase double-buffer ----------
// C = A(MxK bf16 rowmajor) @ Bt(NxK bf16 rowmajor)^T, fp32 acc. K multiple of 32.
// LDS tile rows are 64B; swizzle: byte_col ^= ((row>>1)&3)<<4  (8-way -> 2-way conflict).
// global_load_lds dest stays LINEAR; the source column carries the inverse permutation.

// 128x128 tile, 4 waves. As/Bs are [2][128*32] u16.
DEVFN void gemm_tile_mainloop(const u16* __restrict__ A, const u16* __restrict__ Bt,
                              int m0, int n0, int K, u16* As, u16* Bs, f32x4 acc[4][4]) {
  const int tid = threadIdx.x;
  const int lane = tid & 63, wid = tid >> 6;
  const int wr = wid >> 1, wc = wid & 1;
  const int lr = lane & 15, lg = lane >> 4;
  const int srow = tid >> 2;
  const int scol = ((tid & 3) ^ ((tid >> 3) & 3)) * 8;  // pre-swizzled source col (u16)
  const int axor = ((lr >> 1) & 3) << 4;                // read-side swizzle (bytes)

  const u16* ag0 = A + (size_t)(m0 + srow) * K + scol;
  const u16* ag1 = ag0 + (size_t)64 * K;
  const u16* bg0 = Bt + (size_t)(n0 + srow) * K + scol;
  const u16* bg1 = bg0 + (size_t)64 * K;

  // prologue: stage K-step 0 into buffer 0
  gll16(ag0, As + tid * 8);
  gll16(ag1, As + (tid + 256) * 8);
  gll16(bg0, Bs + tid * 8);
  gll16(bg1, Bs + (tid + 256) * 8);

  int cur = 0;
  for (int k0 = 0; k0 < K; k0 += 32) {
    __syncthreads();  // drains vmcnt: buffer `cur` staged & prev compute on cur^1 done
    if (k0 + 32 < K) {  // issue next-step stage; overlaps with compute below
      int nb = (cur ^ 1) * 4096;
      gll16(ag0 + k0 + 32, As + nb + tid * 8);
      gll16(ag1 + k0 + 32, As + nb + (tid + 256) * 8);
      gll16(bg0 + k0 + 32, Bs + nb + tid * 8);
      gll16(bg1 + k0 + 32, Bs + nb + (tid + 256) * 8);
    }
    const char* Ac = (const char*)(As + cur * 4096);
    const char* Bc = (const char*)(Bs + cur * 4096);
    short8 af[4], bf[4];
#pragma unroll
    for (int i = 0; i < 4; ++i)
      af[i] = *(const short8*)(Ac + (wr * 64 + i * 16 + lr) * 64 + ((lg * 16) ^ axor));
#pragma unroll
    for (int j = 0; j < 4; ++j)
      bf[j] = *(const short8*)(Bc + (wc * 64 + j * 16 + lr) * 64 + ((lg * 16) ^ axor));
#pragma unroll
    for (int i = 0; i < 4; ++i)
#pragma unroll
      for (int j = 0; j < 4; ++j)
        acc[i][j] = __builtin_amdgcn_mfma_f32_16x16x32_bf16(af[i], bf[j], acc[i][j], 0, 0, 0);
    cur ^= 1;
  }
}

// 64x64 tile, 4 waves (for skinny GEMM2: better occupancy). As/Bs are [2][64*32] u16.
DEVFN void gemm64_mainloop(const u16* __restrict__ A, const u16* __restrict__ Bt,
                           int m0, int n0, int K, u16* As, u16* Bs, f32x4 acc[2][2]) {
  const int tid = threadIdx.x;
  const int lane = tid & 63, wid = tid >> 6;
  const int wr = wid >> 1, wc = wid & 1;
  const int lr = lane & 15, lg = lane >> 4;
  const int srow = tid >> 2;
  const int scol = ((tid & 3) ^ ((tid >> 3) & 3)) * 8;
  const int axor = ((lr >> 1) & 3) << 4;

  const u16* ag = A + (size_t)(m0 + srow) * K + scol;
  const u16* bg = Bt + (size_t)(n0 + srow) * K + scol;
  gll16(ag, As + tid * 8);
  gll16(bg, Bs + tid * 8);

  int cur = 0;
  for (int k0 = 0; k0 < K; k0 += 32) {
    __syncthreads();
    if (k0 + 32 < K) {
      int nb = (cur ^ 1) * 2048;
      gll16(ag + k0 + 32, As + nb + tid * 8);
      gll16(bg + k0 + 32, Bs + nb + tid * 8);
    }
    const char* Ac = (const char*)(As + cur * 2048);
    const char* Bc = (const char*)(Bs + cur * 2048);
    short8 af[2], bf[2];
#pragma unroll
    for (int i = 0; i < 2; ++i)
      af[i] = *(const short8*)(Ac + (wr * 32 + i * 16 + lr) * 64 + ((lg * 16) ^ axor));
#pragma unroll
    for (int j = 0; j < 2; ++j)
      bf[j] = *(const short8*)(Bc + (wc * 32 + j * 16 + lr) * 64 + ((lg * 16) ^ axor));
#pragma unroll
    for (int i = 0; i < 2; ++i)
#pragma unroll
      for (int j = 0; j < 2; ++j)
        acc[i][j] = __builtin_amdgcn_mfma_f32_16x16x32_bf16(af[i], bf[j], acc[i][j], 0, 0, 0);
    cur ^= 1;
  }
}

// GEMM1: qkv = x_bf16 @ WqkvT^T + bqkv, split-written as Q[b,s,h,d], K[b,s,h,d] (bf16)
// and V^T[b,h,d,s] (bf16) for the attention PV step.
__global__ __launch_bounds__(256) void gemm_qkv_kernel(
    const u16* __restrict__ A, const u16* __restrict__ Bt, const float* __restrict__ bias,
    u16* __restrict__ Qb, u16* __restrict__ Kb, u16* __restrict__ Vt) {
  __shared__ __align__(16) u16 As[2 * 128 * 32];
  __shared__ __align__(16) u16 Bs[2 * 128 * 32];
  f32x4 acc[4][4];
  const f32x4 z = {0.f, 0.f, 0.f, 0.f};
#pragma unroll
  for (int i = 0; i < 4; ++i)
#pragma unroll
    for (int j = 0; j < 4; ++j) acc[i][j] = z;
  int m0 = blockIdx.y * 128, n0 = blockIdx.x * 128;
  gemm_tile_mainloop(A, Bt, m0, n0, 1024, As, Bs, acc);

  const int lane = threadIdx.x & 63, wid = threadIdx.x >> 6;
  const int wr = wid >> 1, wc = wid & 1, lr = lane & 15, lg = lane >> 4;
#pragma unroll
  for (int j = 0; j < 4; ++j) {
    int col = n0 + wc * 64 + j * 16 + lr;
    float bv = bias[col];
    int c3 = col >> 10;  // uniform per block (128 | 1024)
    int hh = (col >> 6) & 15, dd = col & 63;
#pragma unroll
    for (int i = 0; i < 4; ++i) {
      int row0 = m0 + wr * 64 + i * 16 + lg * 4;  // rows row0..row0+3
      if (c3 == 2) {  // V^T: s consecutive over r -> packed 8B store
        int b = row0 >> 11, s0 = row0 & 2047;
        u16x4 pv = {f2bf(acc[i][j][0] + bv), f2bf(acc[i][j][1] + bv),
                    f2bf(acc[i][j][2] + bv), f2bf(acc[i][j][3] + bv)};
        *(u16x4*)&Vt[(((size_t)b * 16 + hh) * 64 + dd) * 2048 + s0] = pv;
      } else {
        u16* dst = (c3 == 0) ? Qb : Kb;
#pragma unroll
        for (int r = 0; r < 4; ++r)
          dst[(size_t)(row0 + r) * 1024 + (col & 1023)] = f2bf(acc[i][j][r] + bv);
      }
    }
  }
}

// GEMM2: out = (attn_bf16 @ WoT^T + bo) * scale[b], fp32 out. 64x64 tiles.
__global__ __launch_bounds__(256) void gemm_out_kernel(
    const u16* __restrict__ A, const u16* __restrict__ Bt, const float* __restrict__ bo,
    const float* __restrict__ scale, float* __restrict__ out) {
  __shared__ __align__(16) u16 As[2 * 64 * 32];
  __shared__ __align__(16) u16 Bs[2 * 64 * 32];
  f32x4 acc[2][2];
  const f32x4 z = {0.f, 0.f, 0.f, 0.f};
#pragma unroll
  for (int i = 0; i < 2; ++i)
#pragma unroll
    for (int j = 0; j < 2; ++j) acc[i][j] = z;
  int m0 = blockIdx.y * 64, n0 = blockIdx.x * 64;
  gemm64_mainloop(A, Bt, m0, n0, 1024, As, Bs, acc);

  const int lane = threadIdx.x & 63, wid = threadIdx.x >> 6;
  const int wr = wid >> 1, wc = wid & 1, lr = lane & 15, lg = lane >> 4;
#pragma unroll
  for (int j = 0; j < 2; ++j) {
    int col = n0 + wc * 32 + j * 16 + lr;
    float bv = bo[col];
#pragma unroll
    for (int i = 0; i < 2; ++i) {
      int row0 = m0 + wr * 32 + i * 16 + lg * 4;
      float sc = scale[row0 >> 11];
#pragma unroll
      for (int r = 0; r < 2 * 2; ++r) {
      }
#pragma unroll
      for (int r = 0; r < 4; ++r)
        out[(size_t)(row0 + r) * 1024 + col] = (acc[i][j][r] + bv) * sc;
    }
  }
}

// ---------- flash attention with mobius score transform ----------
// grid = B*H*32 blocks (64-query tile), 256 threads = 4 waves, wave w owns 16 queries.
// Swapped QK^T: St = mfma(K_frag, Q_frag) -> lane holds 16 keys of ONE query (q = lane&15).
// All LDS tiles [64][128B] use XOR swizzle byte^=((row&7)<<4): 16-way -> 2-way conflicts.
// K/V double-buffered (T3 2-phase: stage next tile, compute current, one barrier/tile).
__global__ __launch_bounds__(256) void attn_kernel(
    const u16* __restrict__ Qb, const u16* __restrict__ Kb, const u16* __restrict__ Vt,
    const float* __restrict__ mobius, u16* __restrict__ O) {
  __shared__ __align__(16) u16 Qs[64 * 64];
  __shared__ __align__(16) u16 Ks[2][64 * 64];
  __shared__ __align__(16) u16 Vs[2][64 * 64];  // V^T tile: [d][key]
  __shared__ __align__(16) u16 Ps[64 * 64];     // P tile: [query][key], per-wave 16 rows
  const int tid = threadIdx.x;
  const int lane = tid & 63, w = tid >> 6;
  const int lr = lane & 15, lg = lane >> 4;
  // XCD-aware bijective swizzle (nwg=1024, %8==0): each XCD gets 128 consecutive
  // work-items = 4 whole (b,h) groups -> K/V fetched once per XCD.
  const int bid = blockIdx.x;
  const int bidx = (bid & 7) * 128 + (bid >> 3);
  const int qb = bidx & 31, h = (bidx >> 5) & 15, b = bidx >> 9;
  const float msc = mobius[h];

  const int srow = tid >> 3;                       // staging row (0..31)
  const int scol = ((tid & 7) ^ (srow & 7)) * 8;   // pre-swizzled source col (u16)
  const int rxor = (lr & 7) << 4;                  // read-side swizzle (bytes)

  {  // stage Q tile once (rows 0..31 and 32..63; (row&7) identical for both halves)
    const u16* qg = Qb + (size_t)(b * 2048 + qb * 64 + srow) * 1024 + h * 64 + scol;
    gll16(qg, Qs + tid * 8);
    gll16(qg + (size_t)32 * 1024, Qs + (tid + 256) * 8);
  }
  const u16* kg = Kb + (size_t)(b * 2048 + srow) * 1024 + h * 64 + scol;
  const u16* vg = Vt + ((size_t)(b * 16 + h) * 64 + srow) * 2048 + scol;

  // prologue: stage K/V tile 0 into buffer 0
  gll16(kg, Ks[0] + tid * 8);
  gll16(kg + (size_t)32 * 1024, Ks[0] + (tid + 256) * 8);
  gll16(vg, Vs[0] + tid * 8);
  gll16(vg + 32 * 2048, Vs[0] + (tid + 256) * 8);

  float m_run = -3.0e38f, l_run = 0.0f;
  f32x4 acc_o[4];
  const f32x4 z = {0.f, 0.f, 0.f, 0.f};
#pragma unroll
  for (int i = 0; i < 4; ++i) acc_o[i] = z;

  const int qrow = w * 16 + lr;
  int cur = 0;
  for (int kt = 0; kt < 32; ++kt) {
    __syncthreads();  // drains vmcnt: buffer `cur` ready; prev compute on cur^1 done
    if (kt < 31) {    // stage next K/V tile; overlaps with compute below
      const u16* kgn = kg + (size_t)(kt + 1) * 64 * 1024;
      const u16* vgn = vg + (kt + 1) * 64;
      u16* Kn = Ks[cur ^ 1];
      u16* Vn = Vs[cur ^ 1];
      gll16(kgn, Kn + tid * 8);
      gll16(kgn + (size_t)32 * 1024, Kn + (tid + 256) * 8);
      gll16(vgn, Vn + tid * 8);
      gll16(vgn + 32 * 2048, Vn + (tid + 256) * 8);
    }
    const char* Kc = (const char*)Ks[cur];
    const char* Vc = (const char*)Vs[cur];
    const char* Qc = (const char*)Qs;
    const char* Pc = (const char*)Ps;

    // St = K_tile @ Q_wave^T
    f32x4 sacc[4];
#pragma unroll
    for (int i = 0; i < 4; ++i) sacc[i] = z;
#pragma unroll
    for (int ks = 0; ks < 2; ++ks) {
      int cbx = (ks * 64 + lg * 16) ^ rxor;
      short8 qf = *(const short8*)(Qc + qrow * 128 + cbx);
#pragma unroll
      for (int ki = 0; ki < 4; ++ki) {
        short8 kf = *(const short8*)(Kc + (ki * 16 + lr) * 128 + cbx);
        sacc[ki] = __builtin_amdgcn_mfma_f32_16x16x32_bf16(kf, qf, sacc[ki], 0, 0, 0);
      }
    }

    // scale + mobius + online softmax. lane's query = lane&15; keys ki*16+lg*4+r.
    float p[16];
    float tmax = -3.0e38f;
#pragma unroll
    for (int ki = 0; ki < 4; ++ki)
#pragma unroll
      for (int r = 0; r < 4; ++r) {
        float s = sacc[ki][r] * 0.125f;
        s += msc * s / (1.0f + s * s);
        p[ki * 4 + r] = s;
        tmax = fmaxf(tmax, s);
      }
    tmax = fmaxf(tmax, __shfl_xor(tmax, 16));
    tmax = fmaxf(tmax, __shfl_xor(tmax, 32));
    float m_new = fmaxf(m_run, tmax);
    float corr = __expf(m_run - m_new);
    float tsum = 0.f;
#pragma unroll
    for (int i = 0; i < 16; ++i) {
      p[i] = __expf(p[i] - m_new);
      tsum += p[i];
    }
    tsum += __shfl_xor(tsum, 16);
    tsum += __shfl_xor(tsum, 32);
    l_run = l_run * corr + tsum;
    m_run = m_new;

    // write P (bf16) into this wave's private region (swizzled, 8B stores, 2-way)
#pragma unroll
    for (int ki = 0; ki < 4; ++ki) {
      u16x4 pk = {f2bf(p[ki * 4 + 0]), f2bf(p[ki * 4 + 1]), f2bf(p[ki * 4 + 2]),
                  f2bf(p[ki * 4 + 3])};
      *(u16x4*)(Pc + qrow * 128 + ((ki * 32 + lg * 8) ^ rxor)) = pk;
    }

    // rescale O: O-fragment row(query) = lg*4+r
    float c4[4];
#pragma unroll
    for (int r = 0; r < 4; ++r) c4[r] = __shfl(corr, lg * 4 + r);
#pragma unroll
    for (int di = 0; di < 4; ++di)
#pragma unroll
      for (int r = 0; r < 4; ++r) acc_o[di][r] *= c4[r];

    // O += P @ V  (A = P[q][key] rows, B^T = Vs[d][key] rows)
#pragma unroll
    for (int ks = 0; ks < 2; ++ks) {
      int cbx = (ks * 64 + lg * 16) ^ rxor;
      short8 pf = *(const short8*)(Pc + qrow * 128 + cbx);
#pragma unroll
      for (int di = 0; di < 4; ++di) {
        short8 vf = *(const short8*)(Vc + (di * 16 + lr) * 128 + cbx);
        acc_o[di] = __builtin_amdgcn_mfma_f32_16x16x32_bf16(pf, vf, acc_o[di], 0, 0, 0);
      }
    }
    cur ^= 1;
  }

  float linv = 1.0f / l_run;
  float li[4];
#pragma unroll
  for (int r = 0; r < 4; ++r) li[r] = __shfl(linv, lg * 4 + r);
  size_t obase = (size_t)(b * 2048 + qb * 64 + w * 16) * 1024 + h * 64;
#pragma unroll
  for (int di = 0; di < 4; ++di)
#pragma unroll
    for (int r = 0; r < 4; ++r)
      O[obase + (size_t)(lg * 4 + r) * 1024 + di * 16 + lr] = f2bf(acc_o[di][r] * li[r]);
}

// ---------- launch ----------

extern "C" void kernel_launch(void* const* d_in, const int* in_sizes, int n_in,
                              void* d_out, int out_size, void* d_ws, size_t ws_size,
                              hipStream_t stream) {
  const float* x = (const float*)d_in[0];
  const float* Wqkv = (const float*)d_in[1];
  const float* bqkv = (const float*)d_in[2];
  const float* Wo = (const float*)d_in[3];
  const float* bo = (const float*)d_in[4];
  const float* mob = (const float*)d_in[5];
  const float* W1 = (const float*)d_in[6];
  const float* b1 = (const float*)d_in[7];
  const float* W2 = (const float*)d_in[8];
  const float* b2 = (const float*)d_in[9];
  const float* aw = (const float*)d_in[10];
  float* out = (float*)d_out;

  char* ws = (char*)d_ws;
  float* scale = (float*)ws;               // 2 floats
  float* ctx = (float*)(ws + 256);         // 2048 floats
  u16* xbf = (u16*)(ws + 16384);           // 4096x1024
  u16* wqkvT = xbf + (size_t)4096 * 1024;  // 3072x1024
  u16* woT = wqkvT + (size_t)3072 * 1024;  // 1024x1024
  u16* Qb = woT + (size_t)1024 * 1024;     // [B,S,H,64]
  u16* Kb = Qb + (size_t)4096 * 1024;      // [B,S,H,64]
  u16* Vt = Kb + (size_t)4096 * 1024;      // [B,H,64,S]
  u16* attn = Vt + (size_t)4096 * 1024;    // [B,S,D]
  // total: 16KB + 48MB

  hipMemsetAsync(ctx, 0, 2048 * sizeof(float), stream);
  ctx_partial_kernel<<<256, 256, 0, stream>>>(x, ctx);
  adaptive_kernel<<<2, 256, 0, stream>>>(ctx, W1, b1, W2, b2, aw, scale);
  cvt_bf16_kernel<<<4096, 256, 0, stream>>>(x, xbf, 1048576);
  transpose_bf16_kernel<<<dim3(96, 32), 256, 0, stream>>>(Wqkv, wqkvT, 1024, 3072);
  transpose_bf16_kernel<<<dim3(32, 32), 256, 0, stream>>>(Wo, woT, 1024, 1024);
  gemm_qkv_kernel<<<dim3(24, 32), 256, 0, stream>>>(xbf, wqkvT, bqkv, Qb, Kb, Vt);
  attn_kernel<<<1024, 256, 0, stream>>>(Qb, Kb, Vt, mob, attn);
  gemm_out_kernel<<<dim3(16, 64), 256, 0, stream>>>(attn, woT, bo, scale, out);
}

// Round 3
// 272.428 us; speedup vs baseline: 1.5389x; 1.3544x over previous
//
#include <hip/hip_runtime.h>
#include <hip/hip_bf16.h>
#include <stdint.h>

typedef unsigned short u16;
typedef unsigned int u32;
typedef __attribute__((ext_vector_type(8))) short short8;   // 8 bf16 (4 VGPRs) MFMA operand
typedef __attribute__((ext_vector_type(4))) float f32x4;    // MFMA accumulator
typedef __attribute__((ext_vector_type(2))) float f32x2;    // packed-fp32 (v_pk_*) carrier
typedef __attribute__((ext_vector_type(4))) unsigned short u16x4;
typedef __attribute__((ext_vector_type(2))) unsigned int u32x2;

#define DEVFN static __device__ __forceinline__

// ---------- helpers ----------

DEVFN u16 f2bf(float f) {  // RNE float->bf16 (finite inputs)
  u32 u = __float_as_uint(f);
  u = (u + 0x7FFFu + ((u >> 16) & 1u)) >> 16;
  return (u16)u;
}

DEVFN u32 cvtpk_bf16(float lo, float hi) {  // T12: packed f32x2 -> 2xbf16 in one u32
  u32 r;
  asm("v_cvt_pk_bf16_f32 %0, %1, %2" : "=v"(r) : "v"(lo), "v"(hi));
  return r;
}

DEVFN void gll16(const void* g, void* l) {  // async global->LDS, 16B/lane
  __builtin_amdgcn_global_load_lds((const __attribute__((address_space(1))) u32*)g,
                                   (__attribute__((address_space(3))) u32*)l, 16, 0, 0);
}

// ---------- small kernels: adaptive scale path ----------

__global__ void ctx_partial_kernel(const float* __restrict__ x, float* __restrict__ ctx) {
  int blk = blockIdx.x;
  int b = blk >> 7;
  int s0 = (blk & 127) * 16;
  int t = threadIdx.x;
  const float* xb = x + (size_t)b * 2048 * 1024 + (size_t)s0 * 1024;
#pragma unroll
  for (int c = 0; c < 4; ++c) {
    int d = c * 256 + t;
    float sum = 0.f;
#pragma unroll
    for (int s = 0; s < 16; ++s) sum += xb[(size_t)s * 1024 + d];
    atomicAdd(&ctx[b * 1024 + d], sum);
  }
}

// stage 1: h = gelu(ctx/2048 @ W1 + b1). grid 16 = 2b x 8 j-chunks of 64.
__global__ void adaptive1_kernel(const float* __restrict__ ctx, const float* __restrict__ W1,
                                 const float* __restrict__ b1, float* __restrict__ hbuf) {
  int b = blockIdx.x >> 3, jb = blockIdx.x & 7;
  int t = threadIdx.x;
  int j = jb * 64 + (t & 63);
  int part = t >> 6;  // 0..3, each covers 256 d's
  __shared__ float ctxs[1024];
  __shared__ float partial[4][64];
  for (int i = t; i < 1024; i += 256) ctxs[i] = ctx[b * 1024 + i] * (1.0f / 2048.0f);
  __syncthreads();
  float a0 = 0.f, a1 = 0.f;
  int d0 = part * 256;
  for (int d = d0; d < d0 + 256; d += 2) {
    a0 += ctxs[d] * W1[(size_t)d * 512 + j];
    a1 += ctxs[d + 1] * W1[(size_t)(d + 1) * 512 + j];
  }
  partial[part][t & 63] = a0 + a1;
  __syncthreads();
  if (t < 64) {
    float acc = b1[j] + ((partial[0][t] + partial[1][t]) + (partial[2][t] + partial[3][t]));
    hbuf[b * 512 + j] = 0.5f * acc * (1.0f + erff(acc * 0.70710678118654752f));  // exact gelu
  }
}

// stage 2: af = sigmoid(h @ W2 + b2); scale[b] = 1 + aw*mean(af). grid 2.
__global__ void adaptive2_kernel(const float* __restrict__ hbuf, const float* __restrict__ W2,
                                 const float* __restrict__ b2, const float* __restrict__ aw,
                                 float* __restrict__ scale) {
  int b = blockIdx.x;
  int t = threadIdx.x;
  __shared__ float part[256];
  int o = t & 15, seg = t >> 4;  // 16 segs x 32 j's
  float a = 0.f;
  for (int j = seg * 32; j < seg * 32 + 32; ++j) a += hbuf[b * 512 + j] * W2[(size_t)j * 16 + o];
  part[t] = a;
  __syncthreads();
  if (t < 16) {
    float acc = b2[t];
    for (int s2 = 0; s2 < 16; ++s2) acc += part[s2 * 16 + t];
    part[t] = 1.0f / (1.0f + __expf(-acc));
  }
  __syncthreads();
  if (t == 0) {
    float s = 0.f;
    for (int i = 0; i < 16; ++i) s += part[i];
    scale[b] = 1.0f + aw[0] * (s * (1.0f / 16.0f));
  }
}

// ---------- conversion / transpose ----------

__global__ void cvt_bf16_kernel(const float* __restrict__ in, u16* __restrict__ out, int n4) {
  int i = blockIdx.x * blockDim.x + threadIdx.x;
  if (i < n4) {
    float4 v = ((const float4*)in)[i];
    u16x4 o = {f2bf(v.x), f2bf(v.y), f2bf(v.z), f2bf(v.w)};
    ((u16x4*)out)[i] = o;
  }
}

// in: fp32 [K][N] row-major -> out: bf16 [N][K] row-major. grid (N/32, K/32), 256 thr.
__global__ void transpose_bf16_kernel(const float* __restrict__ in, u16* __restrict__ out,
                                      int K, int N) {
  __shared__ u16 tile[32][33];
  int n0 = blockIdx.x * 32, k0 = blockIdx.y * 32;
  int tc = threadIdx.x & 31, tr = threadIdx.x >> 5;  // tr in 0..7
  for (int i = tr; i < 32; i += 8)
    tile[i][tc] = f2bf(in[(size_t)(k0 + i) * N + n0 + tc]);
  __syncthreads();
  for (int i = tr; i < 32; i += 8)
    out[(size_t)(n0 + i) * K + k0 + tc] = tile[tc][i];
}

// ---------- GEMM mainloops: swizzled LDS + 2-phase double-buffer ----------
// C = A(MxK bf16 rowmajor) @ Bt(NxK bf16 rowmajor)^T, fp32 acc. K multiple of 32.
// LDS tile rows are 64B; swizzle: byte_col ^= ((row>>1)&3)<<4  (8-way -> 2-way conflict).
// global_load_lds dest stays LINEAR; the source column carries the inverse permutation.

// 128x128 tile, 4 waves. As/Bs are [2][128*32] u16.
DEVFN void gemm_tile_mainloop(const u16* __restrict__ A, const u16* __restrict__ Bt,
                              int m0, int n0, int K, u16* As, u16* Bs, f32x4 acc[4][4]) {
  const int tid = threadIdx.x;
  const int lane = tid & 63, wid = tid >> 6;
  const int wr = wid >> 1, wc = wid & 1;
  const int lr = lane & 15, lg = lane >> 4;
  const int srow = tid >> 2;
  const int scol = ((tid & 3) ^ ((tid >> 3) & 3)) * 8;  // pre-swizzled source col (u16)
  const int axor = ((lr >> 1) & 3) << 4;                // read-side swizzle (bytes)

  const u16* ag0 = A + (size_t)(m0 + srow) * K + scol;
  const u16* ag1 = ag0 + (size_t)64 * K;
  const u16* bg0 = Bt + (size_t)(n0 + srow) * K + scol;
  const u16* bg1 = bg0 + (size_t)64 * K;

  // prologue: stage K-step 0 into buffer 0
  gll16(ag0, As + tid * 8);
  gll16(ag1, As + (tid + 256) * 8);
  gll16(bg0, Bs + tid * 8);
  gll16(bg1, Bs + (tid + 256) * 8);

  int cur = 0;
  for (int k0 = 0; k0 < K; k0 += 32) {
    __syncthreads();  // drains vmcnt: buffer `cur` staged & prev compute on cur^1 done
    if (k0 + 32 < K) {  // issue next-step stage; overlaps with compute below
      int nb = (cur ^ 1) * 4096;
      gll16(ag0 + k0 + 32, As + nb + tid * 8);
      gll16(ag1 + k0 + 32, As + nb + (tid + 256) * 8);
      gll16(bg0 + k0 + 32, Bs + nb + tid * 8);
      gll16(bg1 + k0 + 32, Bs + nb + (tid + 256) * 8);
    }
    const char* Ac = (const char*)(As + cur * 4096);
    const char* Bc = (const char*)(Bs + cur * 4096);
    short8 af[4], bf[4];
#pragma unroll
    for (int i = 0; i < 4; ++i)
      af[i] = *(const short8*)(Ac + (wr * 64 + i * 16 + lr) * 64 + ((lg * 16) ^ axor));
#pragma unroll
    for (int j = 0; j < 4; ++j)
      bf[j] = *(const short8*)(Bc + (wc * 64 + j * 16 + lr) * 64 + ((lg * 16) ^ axor));
#pragma unroll
    for (int i = 0; i < 4; ++i)
#pragma unroll
      for (int j = 0; j < 4; ++j)
        acc[i][j] = __builtin_amdgcn_mfma_f32_16x16x32_bf16(af[i], bf[j], acc[i][j], 0, 0, 0);
    cur ^= 1;
  }
}

// 64x64 tile, 4 waves (for skinny GEMM2: better occupancy). As/Bs are [2][64*32] u16.
DEVFN void gemm64_mainloop(const u16* __restrict__ A, const u16* __restrict__ Bt,
                           int m0, int n0, int K, u16* As, u16* Bs, f32x4 acc[2][2]) {
  const int tid = threadIdx.x;
  const int lane = tid & 63, wid = tid >> 6;
  const int wr = wid >> 1, wc = wid & 1;
  const int lr = lane & 15, lg = lane >> 4;
  const int srow = tid >> 2;
  const int scol = ((tid & 3) ^ ((tid >> 3) & 3)) * 8;
  const int axor = ((lr >> 1) & 3) << 4;

  const u16* ag = A + (size_t)(m0 + srow) * K + scol;
  const u16* bg = Bt + (size_t)(n0 + srow) * K + scol;
  gll16(ag, As + tid * 8);
  gll16(bg, Bs + tid * 8);

  int cur = 0;
  for (int k0 = 0; k0 < K; k0 += 32) {
    __syncthreads();
    if (k0 + 32 < K) {
      int nb = (cur ^ 1) * 2048;
      gll16(ag + k0 + 32, As + nb + tid * 8);
      gll16(bg + k0 + 32, Bs + nb + tid * 8);
    }
    const char* Ac = (const char*)(As + cur * 2048);
    const char* Bc = (const char*)(Bs + cur * 2048);
    short8 af[2], bf[2];
#pragma unroll
    for (int i = 0; i < 2; ++i)
      af[i] = *(const short8*)(Ac + (wr * 32 + i * 16 + lr) * 64 + ((lg * 16) ^ axor));
#pragma unroll
    for (int j = 0; j < 2; ++j)
      bf[j] = *(const short8*)(Bc + (wc * 32 + j * 16 + lr) * 64 + ((lg * 16) ^ axor));
#pragma unroll
    for (int i = 0; i < 2; ++i)
#pragma unroll
      for (int j = 0; j < 2; ++j)
        acc[i][j] = __builtin_amdgcn_mfma_f32_16x16x32_bf16(af[i], bf[j], acc[i][j], 0, 0, 0);
    cur ^= 1;
  }
}

// GEMM1: qkv = x_bf16 @ WqkvT^T + bqkv, split-written as Q[b,s,h,d] (pre-scaled by 1/8),
// K[b,s,h,d] (bf16) and V^T[b,h,d,s] (bf16) for the attention PV step.
__global__ __launch_bounds__(256) void gemm_qkv_kernel(
    const u16* __restrict__ A, const u16* __restrict__ Bt, const float* __restrict__ bias,
    u16* __restrict__ Qb, u16* __restrict__ Kb, u16* __restrict__ Vt) {
  __shared__ __align__(16) u16 As[2 * 128 * 32];
  __shared__ __align__(16) u16 Bs[2 * 128 * 32];
  f32x4 acc[4][4];
  const f32x4 z = {0.f, 0.f, 0.f, 0.f};
#pragma unroll
  for (int i = 0; i < 4; ++i)
#pragma unroll
    for (int j = 0; j < 4; ++j) acc[i][j] = z;
  int m0 = blockIdx.y * 128, n0 = blockIdx.x * 128;
  gemm_tile_mainloop(A, Bt, m0, n0, 1024, As, Bs, acc);

  const int lane = threadIdx.x & 63, wid = threadIdx.x >> 6;
  const int wr = wid >> 1, wc = wid & 1, lr = lane & 15, lg = lane >> 4;
#pragma unroll
  for (int j = 0; j < 4; ++j) {
    int col = n0 + wc * 64 + j * 16 + lr;
    float bv = bias[col];
    int c3 = col >> 10;  // uniform per block (128 | 1024)
    int hh = (col >> 6) & 15, dd = col & 63;
    float qs = (c3 == 0) ? 0.125f : 1.0f;  // fold 1/sqrt(dh) into Q
#pragma unroll
    for (int i = 0; i < 4; ++i) {
      int row0 = m0 + wr * 64 + i * 16 + lg * 4;  // rows row0..row0+3
      if (c3 == 2) {  // V^T: s consecutive over r -> packed 8B store
        int b = row0 >> 11, s0 = row0 & 2047;
        u16x4 pv = {f2bf(acc[i][j][0] + bv), f2bf(acc[i][j][1] + bv),
                    f2bf(acc[i][j][2] + bv), f2bf(acc[i][j][3] + bv)};
        *(u16x4*)&Vt[(((size_t)b * 16 + hh) * 64 + dd) * 2048 + s0] = pv;
      } else {
        u16* dst = (c3 == 0) ? Qb : Kb;
#pragma unroll
        for (int r = 0; r < 4; ++r)
          dst[(size_t)(row0 + r) * 1024 + (col & 1023)] = f2bf((acc[i][j][r] + bv) * qs);
      }
    }
  }
}

// GEMM2: out = (attn_bf16 @ WoT^T + bo) * scale[b], fp32 out. 64x64 tiles.
__global__ __launch_bounds__(256) void gemm_out_kernel(
    const u16* __restrict__ A, const u16* __restrict__ Bt, const float* __restrict__ bo,
    const float* __restrict__ scale, float* __restrict__ out) {
  __shared__ __align__(16) u16 As[2 * 64 * 32];
  __shared__ __align__(16) u16 Bs[2 * 64 * 32];
  f32x4 acc[2][2];
  const f32x4 z = {0.f, 0.f, 0.f, 0.f};
#pragma unroll
  for (int i = 0; i < 2; ++i)
#pragma unroll
    for (int j = 0; j < 2; ++j) acc[i][j] = z;
  int m0 = blockIdx.y * 64, n0 = blockIdx.x * 64;
  gemm64_mainloop(A, Bt, m0, n0, 1024, As, Bs, acc);

  const int lane = threadIdx.x & 63, wid = threadIdx.x >> 6;
  const int wr = wid >> 1, wc = wid & 1, lr = lane & 15, lg = lane >> 4;
#pragma unroll
  for (int j = 0; j < 2; ++j) {
    int col = n0 + wc * 32 + j * 16 + lr;
    float bv = bo[col];
#pragma unroll
    for (int i = 0; i < 2; ++i) {
      int row0 = m0 + wr * 32 + i * 16 + lg * 4;
      float sc = scale[row0 >> 11];
#pragma unroll
      for (int r = 0; r < 4; ++r)
        out[(size_t)(row0 + r) * 1024 + col] = (acc[i][j][r] + bv) * sc;
    }
  }
}

// ---------- flash attention with mobius score transform ----------
// grid = B*H*32 blocks (64-query tile), 256 threads = 4 waves, wave w owns 16 queries.
// Swapped QK^T: St = mfma(K_frag, Q_frag) -> lane holds 16 keys of ONE query (q = lane&15).
// Q pre-scaled by 1/8 and held in REGISTERS (2x short8/lane). K/V LDS tiles [64][128B]
// XOR-swizzled byte^=((row&7)<<4); double-buffered (T3 2-phase). Softmax math over f32x2
// packed pairs (v_pk_*), rcp for the mobius div, cvt_pk for P->bf16 (T12).
__global__ __launch_bounds__(256) void attn_kernel(
    const u16* __restrict__ Qb, const u16* __restrict__ Kb, const u16* __restrict__ Vt,
    const float* __restrict__ mobius, u16* __restrict__ O) {
  __shared__ __align__(16) u16 Ks[2][64 * 64];
  __shared__ __align__(16) u16 Vs[2][64 * 64];  // V^T tile: [d][key]
  __shared__ __align__(16) u16 Ps[64 * 64];     // P tile: [query][key], per-wave 16 rows
  const int tid = threadIdx.x;
  const int lane = tid & 63, w = tid >> 6;
  const int lr = lane & 15, lg = lane >> 4;
  // XCD-aware bijective swizzle (nwg=1024, %8==0): each XCD gets 128 consecutive
  // work-items = 4 whole (b,h) groups -> K/V fetched once per XCD.
  const int bid = blockIdx.x;
  const int bidx = (bid & 7) * 128 + (bid >> 3);
  const int qb = bidx & 31, h = (bidx >> 5) & 15, b = bidx >> 9;
  const float msc = mobius[h];

  const int srow = tid >> 3;                      // staging row (0..31)
  const int scol = ((tid & 7) ^ (srow & 7)) * 8;  // pre-swizzled source col (u16)
  const int rxor = (lr & 7) << 4;                 // read-side swizzle (bytes)

  // Q fragments in registers: lane needs Q[q = qb*64 + w*16 + lr][k = ks*32 + lg*8 ..+8]
  const u16* qgl =
      Qb + (size_t)(b * 2048 + qb * 64 + w * 16 + lr) * 1024 + h * 64 + lg * 8;
  short8 qf0 = *(const short8*)qgl;
  short8 qf1 = *(const short8*)(qgl + 32);

  const u16* kg = Kb + (size_t)(b * 2048 + srow) * 1024 + h * 64 + scol;
  const u16* vg = Vt + ((size_t)(b * 16 + h) * 64 + srow) * 2048 + scol;

  // prologue: stage K/V tile 0 into buffer 0
  gll16(kg, Ks[0] + tid * 8);
  gll16(kg + (size_t)32 * 1024, Ks[0] + (tid + 256) * 8);
  gll16(vg, Vs[0] + tid * 8);
  gll16(vg + 32 * 2048, Vs[0] + (tid + 256) * 8);

  float m_run = -3.0e38f, l_run = 0.0f;
  f32x4 acc_o[4];
  const f32x4 z = {0.f, 0.f, 0.f, 0.f};
#pragma unroll
  for (int i = 0; i < 4; ++i) acc_o[i] = z;

  const f32x2 one2 = {1.0f, 1.0f};
  const f32x2 msc2 = {msc, msc};
  const int qrow = w * 16 + lr;
  int cur = 0;
  for (int kt = 0; kt < 32; ++kt) {
    __syncthreads();  // drains vmcnt: buffer `cur` ready; prev compute on cur^1 done
    if (kt < 31) {    // stage next K/V tile; overlaps with compute below
      const u16* kgn = kg + (size_t)(kt + 1) * 64 * 1024;
      const u16* vgn = vg + (kt + 1) * 64;
      u16* Kn = Ks[cur ^ 1];
      u16* Vn = Vs[cur ^ 1];
      gll16(kgn, Kn + tid * 8);
      gll16(kgn + (size_t)32 * 1024, Kn + (tid + 256) * 8);
      gll16(vgn, Vn + tid * 8);
      gll16(vgn + 32 * 2048, Vn + (tid + 256) * 8);
    }
    const char* Kc = (const char*)Ks[cur];
    const char* Vc = (const char*)Vs[cur];
    const char* Pc = (const char*)Ps;

    // St = K_tile @ Q_wave^T  (Q already carries the 1/8 scale)
    f32x4 sacc[4];
#pragma unroll
    for (int i = 0; i < 4; ++i) sacc[i] = z;
    {
      int cbx = (lg * 16) ^ rxor;
#pragma unroll
      for (int ki = 0; ki < 4; ++ki) {
        short8 kf = *(const short8*)(Kc + (ki * 16 + lr) * 128 + cbx);
        sacc[ki] = __builtin_amdgcn_mfma_f32_16x16x32_bf16(kf, qf0, sacc[ki], 0, 0, 0);
      }
      cbx = (64 + lg * 16) ^ rxor;
#pragma unroll
      for (int ki = 0; ki < 4; ++ki) {
        short8 kf = *(const short8*)(Kc + (ki * 16 + lr) * 128 + cbx);
        sacc[ki] = __builtin_amdgcn_mfma_f32_16x16x32_bf16(kf, qf1, sacc[ki], 0, 0, 0);
      }
    }

    // mobius + online softmax over packed f32x2 (keys 16ki+lg*4 + {0..3}).
    f32x2 p2[8];
    f32x2 mx = {-3.0e38f, -3.0e38f};
#pragma unroll
    for (int i = 0; i < 8; ++i) {
      int ki = i >> 1, jj = i & 1;
      f32x2 s = {sacc[ki][jj * 2], sacc[ki][jj * 2 + 1]};
      f32x2 d = s * s + one2;  // v_pk_fma
      f32x2 rr = {__builtin_amdgcn_rcpf(d.x), __builtin_amdgcn_rcpf(d.y)};
      f32x2 t = msc2 * (s * rr) + s;  // v_pk_mul + v_pk_fma
      p2[i] = t;
      mx = __builtin_elementwise_max(mx, t);  // v_pk_max
    }
    float tmax = fmaxf(mx.x, mx.y);
    tmax = fmaxf(tmax, __shfl_xor(tmax, 16));
    tmax = fmaxf(tmax, __shfl_xor(tmax, 32));
    float m_new = fmaxf(m_run, tmax);
    float corr = __expf(m_run - m_new);
    f32x2 m2 = {m_new, m_new};
    f32x2 sum2 = {0.f, 0.f};
#pragma unroll
    for (int i = 0; i < 8; ++i) {
      f32x2 e = p2[i] - m2;  // v_pk_add
      f32x2 pe = {__expf(e.x), __expf(e.y)};
      p2[i] = pe;
      sum2 += pe;  // v_pk_add
    }
    float tsum = sum2.x + sum2.y;
    tsum += __shfl_xor(tsum, 16);
    tsum += __shfl_xor(tsum, 32);
    l_run = l_run * corr + tsum;
    m_run = m_new;

    // write P (bf16 via cvt_pk) into this wave's private region (swizzled, 8B stores)
#pragma unroll
    for (int ki = 0; ki < 4; ++ki) {
      u32x2 pw = {cvtpk_bf16(p2[2 * ki].x, p2[2 * ki].y),
                  cvtpk_bf16(p2[2 * ki + 1].x, p2[2 * ki + 1].y)};
      *(u32x2*)(Pc + qrow * 128 + ((ki * 32 + lg * 8) ^ rxor)) = pw;
    }

    // rescale O: O-fragment row(query) = lg*4+r
    float c4[4];
#pragma unroll
    for (int r = 0; r < 4; ++r) c4[r] = __shfl(corr, lg * 4 + r);
#pragma unroll
    for (int di = 0; di < 4; ++di)
#pragma unroll
      for (int r = 0; r < 4; ++r) acc_o[di][r] *= c4[r];

    // O += P @ V  (A = P[q][key] rows, B^T = Vs[d][key] rows)
#pragma unroll
    for (int ks = 0; ks < 2; ++ks) {
      int cbx = (ks * 64 + lg * 16) ^ rxor;
      short8 pf = *(const short8*)(Pc + qrow * 128 + cbx);
#pragma unroll
      for (int di = 0; di < 4; ++di) {
        short8 vf = *(const short8*)(Vc + (di * 16 + lr) * 128 + cbx);
        acc_o[di] = __builtin_amdgcn_mfma_f32_16x16x32_bf16(pf, vf, acc_o[di], 0, 0, 0);
      }
    }
    cur ^= 1;
  }

  float linv = 1.0f / l_run;
  float li[4];
#pragma unroll
  for (int r = 0; r < 4; ++r) li[r] = __shfl(linv, lg * 4 + r);
  size_t obase = (size_t)(b * 2048 + qb * 64 + w * 16) * 1024 + h * 64;
#pragma unroll
  for (int di = 0; di < 4; ++di)
#pragma unroll
    for (int r = 0; r < 4; ++r)
      O[obase + (size_t)(lg * 4 + r) * 1024 + di * 16 + lr] = f2bf(acc_o[di][r] * li[r]);
}

// ---------- launch ----------

extern "C" void kernel_launch(void* const* d_in, const int* in_sizes, int n_in,
                              void* d_out, int out_size, void* d_ws, size_t ws_size,
                              hipStream_t stream) {
  const float* x = (const float*)d_in[0];
  const float* Wqkv = (const float*)d_in[1];
  const float* bqkv = (const float*)d_in[2];
  const float* Wo = (const float*)d_in[3];
  const float* bo = (const float*)d_in[4];
  const float* mob = (const float*)d_in[5];
  const float* W1 = (const float*)d_in[6];
  const float* b1 = (const float*)d_in[7];
  const float* W2 = (const float*)d_in[8];
  const float* b2 = (const float*)d_in[9];
  const float* aw = (const float*)d_in[10];
  float* out = (float*)d_out;

  char* ws = (char*)d_ws;
  float* scale = (float*)ws;               // 2 floats
  float* ctx = (float*)(ws + 256);         // 2048 floats
  float* hbuf = (float*)(ws + 8192);       // 2x512 floats
  u16* xbf = (u16*)(ws + 16384);           // 4096x1024
  u16* wqkvT = xbf + (size_t)4096 * 1024;  // 3072x1024
  u16* woT = wqkvT + (size_t)3072 * 1024;  // 1024x1024
  u16* Qb = woT + (size_t)1024 * 1024;     // [B,S,H,64] (pre-scaled by 1/8)
  u16* Kb = Qb + (size_t)4096 * 1024;      // [B,S,H,64]
  u16* Vt = Kb + (size_t)4096 * 1024;      // [B,H,64,S]
  u16* attn = Vt + (size_t)4096 * 1024;    // [B,S,D]
  // total: 16KB + 48MB

  hipMemsetAsync(ctx, 0, 2048 * sizeof(float), stream);
  ctx_partial_kernel<<<256, 256, 0, stream>>>(x, ctx);
  adaptive1_kernel<<<16, 256, 0, stream>>>(ctx, W1, b1, hbuf);
  adaptive2_kernel<<<2, 256, 0, stream>>>(hbuf, W2, b2, aw, scale);
  cvt_bf16_kernel<<<4096, 256, 0, stream>>>(x, xbf, 1048576);
  transpose_bf16_kernel<<<dim3(96, 32), 256, 0, stream>>>(Wqkv, wqkvT, 1024, 3072);
  transpose_bf16_kernel<<<dim3(32, 32), 256, 0, stream>>>(Wo, woT, 1024, 1024);
  gemm_qkv_kernel<<<dim3(24, 32), 256, 0, stream>>>(xbf, wqkvT, bqkv, Qb, Kb, Vt);
  attn_kernel<<<1024, 256, 0, stream>>>(Qb, Kb, Vt, mob, attn);
  gemm_out_kernel<<<dim3(16, 64), 256, 0, stream>>>(attn, woT, bo, scale, out);
}